// Round 6
// baseline (1475.513 us; speedup 1.0000x reference)
//
#include <hip/hip_runtime.h>
#include <stdint.h>

// JTMPN on MI355X — round 6: sorted-sweep gather.
// All prior gather variants pin at ~10.7 B/cy/CU (miss-latency x MSHR bound).
// Lever: process refs in ascending msg-id order so all waves chip-wide sweep
// a narrow band of the 75.5MB table -> L2/L3-band hits, lower latency, higher
// sustained rate. Per-wave 128-key bitonic sort in LDS (~0.5us), 8-row f32
// accumulators in VGPRs, scalar-switch slot dispatch. GEMMs = r4 (XCD swizzle).

#define MAX_NB 15
#define HID 512
#define NA 32768
#define NB 65536
#define NMESS 8192

typedef unsigned short u16;
typedef unsigned int u32;
typedef __bf16 bf16x8 __attribute__((ext_vector_type(8)));
typedef float f32x4 __attribute__((ext_vector_type(4)));

__device__ __forceinline__ u16 f2bf(float f) {
  u32 u = __builtin_bit_cast(u32, f);
  u32 r = (u + 0x7fffu + ((u >> 16) & 1u)) >> 16;
  return (u16)r;
}
__device__ __forceinline__ float bf2f(u16 b) {
  u32 u = ((u32)b) << 16;
  return __builtin_bit_cast(float, u);
}
__device__ __forceinline__ float bflo(u32 u) {
  return __builtin_bit_cast(float, u << 16);
}
__device__ __forceinline__ float bfhi(u32 u) {
  return __builtin_bit_cast(float, u & 0xffff0000u);
}

__device__ __forceinline__ void async16(const u16* g, u16* l) {
  __builtin_amdgcn_global_load_lds(
      (const __attribute__((address_space(1))) u32*)g,
      (__attribute__((address_space(3))) u32*)l, 16, 0, 0);
}

// ---------------- prep: fp32 -> bf16 conversions / transposes ----------------
__global__ __launch_bounds__(256) void prep_kernel(
    const float* __restrict__ fbonds, const float* __restrict__ tree,
    const float* __restrict__ Wi, const float* __restrict__ Wh,
    const float* __restrict__ Wo, u16* __restrict__ msg,
    u16* __restrict__ fbpad, u16* __restrict__ wi_t, u16* __restrict__ wh_t,
    u16* __restrict__ wo_t) {
  int t = blockIdx.x * 256 + threadIdx.x;
  const int N0 = NMESS * HID;  // 4194304
  const int N1 = NB * 64;      // 4194304
  const int N2 = 512 * 64;
  const int N3 = 512 * 512;
  const int N4 = 512 * 576;
  if (t < N0) { msg[t] = f2bf(tree[t]); return; }
  t -= N0;
  if (t < N1) {
    int row = t >> 6, c = t & 63;
    fbpad[t] = (c < 40) ? f2bf(fbonds[row * 40 + c]) : (u16)0;
    return;
  }
  t -= N1;
  if (t < N2) {
    int n = t >> 6, k = t & 63;
    wi_t[t] = (k < 40) ? f2bf(Wi[k * 512 + n]) : (u16)0;
    return;
  }
  t -= N2;
  if (t < N3) {
    int n = t >> 9, k = t & 511;
    wh_t[t] = f2bf(Wh[k * 512 + n]);
    return;
  }
  t -= N3;
  if (t < N4) {
    int n = t / 576, k = t - n * 576;
    float v = 0.f;
    if (k < 512) v = Wo[(35 + k) * 512 + n];        // nei part
    else if (k < 547) v = Wo[(k - 512) * 512 + n];  // fatoms part
    wo_t[t] = f2bf(v);
    return;
  }
}

// ---------------- sorted-sweep gather ----------------
// Block: 256 thr = 4 waves; wave owns 8 rows (120 refs). Keys (id<<3)|slot
// bitonic-sorted (128, pad key=0 -> adds zero row 0 to slot 0: harmless).
// Accumulate into 64 f32 VGPRs via scalar switch; 4-deep load pipeline.
#define ACC8(S)                                                       \
  {                                                                   \
    acc[S * 8 + 0] += bflo(v.x); acc[S * 8 + 1] += bfhi(v.x);         \
    acc[S * 8 + 2] += bflo(v.y); acc[S * 8 + 3] += bfhi(v.y);         \
    acc[S * 8 + 4] += bflo(v.z); acc[S * 8 + 5] += bfhi(v.z);         \
    acc[S * 8 + 6] += bflo(v.w); acc[S * 8 + 7] += bfhi(v.w);         \
  }

template <int ATOMS>
__global__ __launch_bounds__(256) void gather_sorted(
    const u16* __restrict__ msg, const int* __restrict__ graph,
    const float* __restrict__ fatoms, u16* __restrict__ outbuf) {
  __shared__ u32 sk[4][128];
  const int lane = threadIdx.x & 63;
  const int w = threadIdx.x >> 6;
  u32* mysk = sk[w];
  const int rowBase = (blockIdx.x * 4 + w) * 8;
  const int OSTRIDE = ATOMS ? 576 : HID;
  const int* gp = graph + rowBase * MAX_NB;  // 120 refs

  // load keys (ref r -> local row r/15 via mul-shift)
  {
    int r0 = lane;
    u32 k0 = ((u32)gp[r0] << 3) | ((u32)(r0 * 2185) >> 15);
    mysk[r0] = k0;
    int r1 = lane + 64;
    u32 k1 = (r1 < 120) ? (((u32)gp[r1] << 3) | ((u32)(r1 * 2185) >> 15)) : 0u;
    mysk[r1] = k1;
  }

  // bitonic sort 128 (28 rounds); pairs disjoint within a round
  for (int k = 2; k <= 128; k <<= 1) {
    for (int j = k >> 1; j > 0; j >>= 1) {
      __syncthreads();
      int i = ((lane & ~(j - 1)) << 1) | (lane & (j - 1));
      int h = i | j;
      u32 a = mysk[i], b = mysk[h];
      bool up = ((i & k) == 0);
      if ((a > b) == up) { mysk[i] = b; mysk[h] = a; }
    }
  }
  __syncthreads();

  float acc[64];
#pragma unroll
  for (int i = 0; i < 64; i++) acc[i] = 0.f;

  for (int e = 0; e < 128; e += 4) {
    int kk[4];
    uint4 vv[4];
#pragma unroll
    for (int q = 0; q < 4; q++)
      kk[q] = __builtin_amdgcn_readfirstlane((int)mysk[e + q]);
#pragma unroll
    for (int q = 0; q < 4; q++)
      vv[q] = *(const uint4*)(msg + (size_t)((u32)kk[q] >> 3) * HID + lane * 8);
#pragma unroll
    for (int q = 0; q < 4; q++) {
      uint4 v = vv[q];
      switch (kk[q] & 7) {
        case 0: ACC8(0); break;
        case 1: ACC8(1); break;
        case 2: ACC8(2); break;
        case 3: ACC8(3); break;
        case 4: ACC8(4); break;
        case 5: ACC8(5); break;
        case 6: ACC8(6); break;
        case 7: ACC8(7); break;
      }
    }
  }

#pragma unroll
  for (int s = 0; s < 8; s++) {
    uint4 o;
    o.x = (u32)f2bf(acc[s * 8 + 0]) | ((u32)f2bf(acc[s * 8 + 1]) << 16);
    o.y = (u32)f2bf(acc[s * 8 + 2]) | ((u32)f2bf(acc[s * 8 + 3]) << 16);
    o.z = (u32)f2bf(acc[s * 8 + 4]) | ((u32)f2bf(acc[s * 8 + 5]) << 16);
    o.w = (u32)f2bf(acc[s * 8 + 6]) | ((u32)f2bf(acc[s * 8 + 7]) << 16);
    u16* orow = outbuf + (size_t)(rowBase + s) * OSTRIDE;
    *(uint4*)(orow + lane * 8) = o;
    if (ATOMS) {
      float tv = (lane < 35) ? fatoms[(size_t)(rowBase + s) * 35 + lane] : 0.f;
      orow[512 + lane] = f2bf(tv);
    }
  }
}

// ---------------- 128x128 bf16 MFMA GEMM, XCD-swizzled 1D grid ---------------
// EPI 0: binput=acc, msg=relu(acc);  EPI 1: msg=relu(acc+binput);
// EPI 2: out[mol] = mean(relu(acc+bias))
template <int EPI>
__global__ __launch_bounds__(256) void gemm_k(
    const u16* __restrict__ A, const u16* __restrict__ Bt, int K, int mtx,
    u16* __restrict__ binput, u16* __restrict__ msgout,
    const float* __restrict__ bo, const int* __restrict__ scope,
    float* __restrict__ out) {
  __shared__ __align__(16) u16 As[128 * 32];
  __shared__ __align__(16) u16 Bs[128 * 32];
  const int L = blockIdx.x;
  const int xcd = L & 7;
  const int q = L >> 3;
  const int mBase = (xcd * mtx + (q >> 2)) * 128;
  const int nBase = (q & 3) * 128;
  const int t = threadIdx.x;
  const int lane = t & 63;
  const int w = t >> 6;
  const int wm = w & 1, wn = w >> 1;
  const int r = t >> 2;
  const int c8 = (t & 3) * 8;
  const int q8 = (lane >> 4) * 8;
  const int l15 = lane & 15;

  f32x4 acc[4][4];
#pragma unroll
  for (int i = 0; i < 4; i++)
#pragma unroll
    for (int j = 0; j < 4; j++)
#pragma unroll
      for (int rg = 0; rg < 4; rg++) acc[i][j][rg] = 0.f;

  for (int kb = 0; kb < K; kb += 32) {
    __syncthreads();
    async16(A + (size_t)(mBase + r) * K + kb + c8, As + r * 32 + c8);
    async16(A + (size_t)(mBase + r + 64) * K + kb + c8, As + (r + 64) * 32 + c8);
    async16(Bt + (size_t)(nBase + r) * K + kb + c8, Bs + r * 32 + c8);
    async16(Bt + (size_t)(nBase + r + 64) * K + kb + c8, Bs + (r + 64) * 32 + c8);
    __syncthreads();
    bf16x8 av[4], bv[4];
#pragma unroll
    for (int i = 0; i < 4; i++)
      av[i] = *(const bf16x8*)(As + (wm * 64 + i * 16 + l15) * 32 + q8);
#pragma unroll
    for (int j = 0; j < 4; j++)
      bv[j] = *(const bf16x8*)(Bs + (wn * 64 + j * 16 + l15) * 32 + q8);
#pragma unroll
    for (int i = 0; i < 4; i++)
#pragma unroll
      for (int j = 0; j < 4; j++)
        acc[i][j] = __builtin_amdgcn_mfma_f32_16x16x32_bf16(av[i], bv[j],
                                                            acc[i][j], 0, 0, 0);
  }

  if (EPI == 2) {
#pragma unroll
    for (int m = 0; m < 2; m++) {
      int mol = (mBase + wm * 64 + m * 32) >> 5;
      float inv_le = 1.0f / (float)scope[mol * 2 + 1];
#pragma unroll
      for (int j = 0; j < 4; j++) {
        int col = nBase + wn * 64 + j * 16 + l15;
        float bias = bo[col];
        float s = 0.f;
#pragma unroll
        for (int i = 2 * m; i < 2 * m + 2; i++)
#pragma unroll
          for (int rg = 0; rg < 4; rg++)
            s += fmaxf(acc[i][j][rg] + bias, 0.f);
        s += __shfl_xor(s, 16, 64);
        s += __shfl_xor(s, 32, 64);
        if (lane < 16) out[(size_t)mol * HID + col] = s * inv_le;
      }
    }
  } else {
#pragma unroll
    for (int i = 0; i < 4; i++) {
      int row = mBase + wm * 64 + i * 16 + (lane >> 4) * 4;
#pragma unroll
      for (int j = 0; j < 4; j++) {
        int col = nBase + wn * 64 + j * 16 + l15;
#pragma unroll
        for (int rg = 0; rg < 4; rg++) {
          float v = acc[i][j][rg];
          size_t gi = (size_t)(row + rg) * HID + col;
          if (EPI == 0) {
            binput[gi] = f2bf(v);
            msgout[gi + (size_t)NMESS * HID] = f2bf(fmaxf(v, 0.f));
          } else {
            v += bf2f(binput[gi]);
            msgout[gi + (size_t)NMESS * HID] = f2bf(fmaxf(v, 0.f));
          }
        }
      }
    }
  }
}

// ---------------- launch ----------------
extern "C" void kernel_launch(void* const* d_in, const int* in_sizes, int n_in,
                              void* d_out, int out_size, void* d_ws,
                              size_t ws_size, hipStream_t stream) {
  const float* fatoms = (const float*)d_in[0];
  const float* fbonds = (const float*)d_in[1];
  const int* agraph = (const int*)d_in[2];
  const int* bgraph = (const int*)d_in[3];
  const int* scope = (const int*)d_in[4];
  const float* tree = (const float*)d_in[5];
  const float* Wi = (const float*)d_in[6];
  const float* Wh = (const float*)d_in[7];
  const float* Wo = (const float*)d_in[8];
  const float* bo = (const float*)d_in[9];
  float* out = (float*)d_out;

  char* ws = (char*)d_ws;
  u16* msg = (u16*)(ws);
  u16* binput = (u16*)(ws + 75497472ull);
  u16* nei = (u16*)(ws + 142606336ull);
  u16* wi_t = (u16*)(ws + 209715200ull);
  u16* wh_t = (u16*)(ws + 209780736ull);
  u16* wo_t = (u16*)(ws + 210305024ull);
  u16* fbpad = nei;     // alias: fbpad dead before first gather writes nei
  u16* ainput = binput; // alias: binput dead after last EPI=1 gemm

  prep_kernel<<<35072, 256, 0, stream>>>(fbonds, tree, Wi, Wh, Wo, msg, fbpad,
                                         wi_t, wh_t, wo_t);

  // init: M=65536 -> 512 mtiles, 64 per XCD
  gemm_k<0><<<2048, 256, 0, stream>>>(fbpad, wi_t, 64, 64, binput, msg,
                                      nullptr, nullptr, nullptr);
  for (int d = 0; d < 5; d++) {
    gather_sorted<0><<<NB / 32, 256, 0, stream>>>(msg, bgraph, nullptr, nei);
    gemm_k<1><<<2048, 256, 0, stream>>>(nei, wh_t, 512, 64, binput, msg,
                                        nullptr, nullptr, nullptr);
  }
  gather_sorted<1><<<NA / 32, 256, 0, stream>>>(msg, agraph, fatoms, ainput);
  // out: M=32768 -> 256 mtiles, 32 per XCD
  gemm_k<2><<<1024, 256, 0, stream>>>(ainput, wo_t, 576, 32, nullptr, nullptr,
                                      bo, scope, out);
}

// Round 7
// 1249.298 us; speedup vs baseline: 1.1811x; 1.1811x over previous
//
#include <hip/hip_runtime.h>
#include <stdint.h>

// JTMPN on MI355X — round 7: revert to best-known config (r4-class, 1274us):
// simple pinned-rate gather (r1/r3 form) + XCD-swizzled GEMMs. New: gather
// rows partitioned by XCD to MATCH the gemm's XCD row ranges, so nei is
// produced into the same per-XCD L2 that consumes it (first-read A hits L2).
// Model: whole iteration is CU-delivery-bound (~10.7 B/cy/CU); only L2-fast-
// path bytes are compressible.

#define MAX_NB 15
#define HID 512
#define NA 32768
#define NB 65536
#define NMESS 8192

typedef unsigned short u16;
typedef unsigned int u32;
typedef __bf16 bf16x8 __attribute__((ext_vector_type(8)));
typedef float f32x4 __attribute__((ext_vector_type(4)));

__device__ __forceinline__ u16 f2bf(float f) {
  u32 u = __builtin_bit_cast(u32, f);
  u32 r = (u + 0x7fffu + ((u >> 16) & 1u)) >> 16;
  return (u16)r;
}
__device__ __forceinline__ float bf2f(u16 b) {
  u32 u = ((u32)b) << 16;
  return __builtin_bit_cast(float, u);
}
__device__ __forceinline__ float bflo(u32 u) {
  return __builtin_bit_cast(float, u << 16);
}
__device__ __forceinline__ float bfhi(u32 u) {
  return __builtin_bit_cast(float, u & 0xffff0000u);
}

__device__ __forceinline__ void async16(const u16* g, u16* l) {
  __builtin_amdgcn_global_load_lds(
      (const __attribute__((address_space(1))) u32*)g,
      (__attribute__((address_space(3))) u32*)l, 16, 0, 0);
}

// ---------------- prep: fp32 -> bf16 conversions / transposes ----------------
__global__ __launch_bounds__(256) void prep_kernel(
    const float* __restrict__ fbonds, const float* __restrict__ tree,
    const float* __restrict__ Wi, const float* __restrict__ Wh,
    const float* __restrict__ Wo, u16* __restrict__ msg,
    u16* __restrict__ fbpad, u16* __restrict__ wi_t, u16* __restrict__ wh_t,
    u16* __restrict__ wo_t) {
  int t = blockIdx.x * 256 + threadIdx.x;
  const int N0 = NMESS * HID;  // 4194304
  const int N1 = NB * 64;      // 4194304
  const int N2 = 512 * 64;
  const int N3 = 512 * 512;
  const int N4 = 512 * 576;
  if (t < N0) { msg[t] = f2bf(tree[t]); return; }
  t -= N0;
  if (t < N1) {
    int row = t >> 6, c = t & 63;
    fbpad[t] = (c < 40) ? f2bf(fbonds[row * 40 + c]) : (u16)0;
    return;
  }
  t -= N1;
  if (t < N2) {
    int n = t >> 6, k = t & 63;
    wi_t[t] = (k < 40) ? f2bf(Wi[k * 512 + n]) : (u16)0;
    return;
  }
  t -= N2;
  if (t < N3) {
    int n = t >> 9, k = t & 511;
    wh_t[t] = f2bf(Wh[k * 512 + n]);
    return;
  }
  t -= N3;
  if (t < N4) {
    int n = t / 576, k = t - n * 576;
    float v = 0.f;
    if (k < 512) v = Wo[(35 + k) * 512 + n];        // nei part
    else if (k < 547) v = Wo[(k - 512) * 512 + n];  // fatoms part
    wo_t[t] = f2bf(v);
    return;
  }
}

// ---------------- gather-sum: wave per row, XCD-affine row mapping ----------
// Block b serves 4 rows in XCD (b&7)'s range [xcd*rowsPerXcd, ...), matching
// the gemm's m-tile XCD ownership -> nei produced into the consuming L2.
__global__ __launch_bounds__(256) void gather_bonds(
    const u16* __restrict__ msg, const int* __restrict__ bgraph,
    u16* __restrict__ nei) {
  const int xcd = blockIdx.x & 7;
  const int chunk = blockIdx.x >> 3;
  int row = xcd * (NB / 8) + chunk * 4 + (threadIdx.x >> 6);
  int lane = threadIdx.x & 63;
  const int* idxp = bgraph + row * MAX_NB;
  float acc[8] = {0, 0, 0, 0, 0, 0, 0, 0};
#pragma unroll
  for (int j = 0; j < MAX_NB; j++) {
    int id = idxp[j];
    uint4 v = *(const uint4*)(msg + (size_t)id * HID + lane * 8);
    acc[0] += bflo(v.x); acc[1] += bfhi(v.x);
    acc[2] += bflo(v.y); acc[3] += bfhi(v.y);
    acc[4] += bflo(v.z); acc[5] += bfhi(v.z);
    acc[6] += bflo(v.w); acc[7] += bfhi(v.w);
  }
  uint4 o;
  o.x = (u32)f2bf(acc[0]) | ((u32)f2bf(acc[1]) << 16);
  o.y = (u32)f2bf(acc[2]) | ((u32)f2bf(acc[3]) << 16);
  o.z = (u32)f2bf(acc[4]) | ((u32)f2bf(acc[5]) << 16);
  o.w = (u32)f2bf(acc[6]) | ((u32)f2bf(acc[7]) << 16);
  *(uint4*)(nei + (size_t)row * HID + lane * 8) = o;
}

// atom gather: same XCD-affine mapping; builds ainput [nei | fatoms | pad]
__global__ __launch_bounds__(256) void gather_atoms(
    const u16* __restrict__ msg, const int* __restrict__ agraph,
    const float* __restrict__ fatoms, u16* __restrict__ ainput) {
  const int xcd = blockIdx.x & 7;
  const int chunk = blockIdx.x >> 3;
  int row = xcd * (NA / 8) + chunk * 4 + (threadIdx.x >> 6);
  int lane = threadIdx.x & 63;
  const int* idxp = agraph + row * MAX_NB;
  float acc[8] = {0, 0, 0, 0, 0, 0, 0, 0};
#pragma unroll
  for (int j = 0; j < MAX_NB; j++) {
    int id = idxp[j];
    uint4 v = *(const uint4*)(msg + (size_t)id * HID + lane * 8);
    acc[0] += bflo(v.x); acc[1] += bfhi(v.x);
    acc[2] += bflo(v.y); acc[3] += bfhi(v.y);
    acc[4] += bflo(v.z); acc[5] += bfhi(v.z);
    acc[6] += bflo(v.w); acc[7] += bfhi(v.w);
  }
  uint4 o;
  o.x = (u32)f2bf(acc[0]) | ((u32)f2bf(acc[1]) << 16);
  o.y = (u32)f2bf(acc[2]) | ((u32)f2bf(acc[3]) << 16);
  o.z = (u32)f2bf(acc[4]) | ((u32)f2bf(acc[5]) << 16);
  o.w = (u32)f2bf(acc[6]) | ((u32)f2bf(acc[7]) << 16);
  u16* arow = ainput + (size_t)row * 576;
  *(uint4*)(arow + lane * 8) = o;
  float tv = (lane < 35) ? fatoms[(size_t)row * 35 + lane] : 0.f;
  arow[512 + lane] = f2bf(tv);
}

// ---------------- 128x128 bf16 MFMA GEMM, XCD-swizzled 1D grid ---------------
// EPI 0: binput=acc, msg=relu(acc);  EPI 1: msg=relu(acc+binput);
// EPI 2: out[mol] = mean(relu(acc+bias))
template <int EPI>
__global__ __launch_bounds__(256) void gemm_k(
    const u16* __restrict__ A, const u16* __restrict__ Bt, int K, int mtx,
    u16* __restrict__ binput, u16* __restrict__ msgout,
    const float* __restrict__ bo, const int* __restrict__ scope,
    float* __restrict__ out) {
  __shared__ __align__(16) u16 As[128 * 32];
  __shared__ __align__(16) u16 Bs[128 * 32];
  const int L = blockIdx.x;
  const int xcd = L & 7;
  const int q = L >> 3;
  const int mBase = (xcd * mtx + (q >> 2)) * 128;
  const int nBase = (q & 3) * 128;
  const int t = threadIdx.x;
  const int lane = t & 63;
  const int w = t >> 6;
  const int wm = w & 1, wn = w >> 1;
  const int r = t >> 2;
  const int c8 = (t & 3) * 8;
  const int q8 = (lane >> 4) * 8;
  const int l15 = lane & 15;

  f32x4 acc[4][4];
#pragma unroll
  for (int i = 0; i < 4; i++)
#pragma unroll
    for (int j = 0; j < 4; j++)
#pragma unroll
      for (int rg = 0; rg < 4; rg++) acc[i][j][rg] = 0.f;

  for (int kb = 0; kb < K; kb += 32) {
    __syncthreads();
    async16(A + (size_t)(mBase + r) * K + kb + c8, As + r * 32 + c8);
    async16(A + (size_t)(mBase + r + 64) * K + kb + c8, As + (r + 64) * 32 + c8);
    async16(Bt + (size_t)(nBase + r) * K + kb + c8, Bs + r * 32 + c8);
    async16(Bt + (size_t)(nBase + r + 64) * K + kb + c8, Bs + (r + 64) * 32 + c8);
    __syncthreads();
    bf16x8 av[4], bv[4];
#pragma unroll
    for (int i = 0; i < 4; i++)
      av[i] = *(const bf16x8*)(As + (wm * 64 + i * 16 + l15) * 32 + q8);
#pragma unroll
    for (int j = 0; j < 4; j++)
      bv[j] = *(const bf16x8*)(Bs + (wn * 64 + j * 16 + l15) * 32 + q8);
#pragma unroll
    for (int i = 0; i < 4; i++)
#pragma unroll
      for (int j = 0; j < 4; j++)
        acc[i][j] = __builtin_amdgcn_mfma_f32_16x16x32_bf16(av[i], bv[j],
                                                            acc[i][j], 0, 0, 0);
  }

  if (EPI == 2) {
#pragma unroll
    for (int m = 0; m < 2; m++) {
      int mol = (mBase + wm * 64 + m * 32) >> 5;
      float inv_le = 1.0f / (float)scope[mol * 2 + 1];
#pragma unroll
      for (int j = 0; j < 4; j++) {
        int col = nBase + wn * 64 + j * 16 + l15;
        float bias = bo[col];
        float s = 0.f;
#pragma unroll
        for (int i = 2 * m; i < 2 * m + 2; i++)
#pragma unroll
          for (int rg = 0; rg < 4; rg++)
            s += fmaxf(acc[i][j][rg] + bias, 0.f);
        s += __shfl_xor(s, 16, 64);
        s += __shfl_xor(s, 32, 64);
        if (lane < 16) out[(size_t)mol * HID + col] = s * inv_le;
      }
    }
  } else {
#pragma unroll
    for (int i = 0; i < 4; i++) {
      int row = mBase + wm * 64 + i * 16 + (lane >> 4) * 4;
#pragma unroll
      for (int j = 0; j < 4; j++) {
        int col = nBase + wn * 64 + j * 16 + l15;
#pragma unroll
        for (int rg = 0; rg < 4; rg++) {
          float v = acc[i][j][rg];
          size_t gi = (size_t)(row + rg) * HID + col;
          if (EPI == 0) {
            binput[gi] = f2bf(v);
            msgout[gi + (size_t)NMESS * HID] = f2bf(fmaxf(v, 0.f));
          } else {
            v += bf2f(binput[gi]);
            msgout[gi + (size_t)NMESS * HID] = f2bf(fmaxf(v, 0.f));
          }
        }
      }
    }
  }
}

// ---------------- launch ----------------
extern "C" void kernel_launch(void* const* d_in, const int* in_sizes, int n_in,
                              void* d_out, int out_size, void* d_ws,
                              size_t ws_size, hipStream_t stream) {
  const float* fatoms = (const float*)d_in[0];
  const float* fbonds = (const float*)d_in[1];
  const int* agraph = (const int*)d_in[2];
  const int* bgraph = (const int*)d_in[3];
  const int* scope = (const int*)d_in[4];
  const float* tree = (const float*)d_in[5];
  const float* Wi = (const float*)d_in[6];
  const float* Wh = (const float*)d_in[7];
  const float* Wo = (const float*)d_in[8];
  const float* bo = (const float*)d_in[9];
  float* out = (float*)d_out;

  char* ws = (char*)d_ws;
  u16* msg = (u16*)(ws);
  u16* binput = (u16*)(ws + 75497472ull);
  u16* nei = (u16*)(ws + 142606336ull);
  u16* wi_t = (u16*)(ws + 209715200ull);
  u16* wh_t = (u16*)(ws + 209780736ull);
  u16* wo_t = (u16*)(ws + 210305024ull);
  u16* fbpad = nei;     // alias: fbpad dead before first gather writes nei
  u16* ainput = binput; // alias: binput dead after last EPI=1 gemm

  prep_kernel<<<35072, 256, 0, stream>>>(fbonds, tree, Wi, Wh, Wo, msg, fbpad,
                                         wi_t, wh_t, wo_t);

  // init: M=65536 -> 512 mtiles, 64 per XCD
  gemm_k<0><<<2048, 256, 0, stream>>>(fbpad, wi_t, 64, 64, binput, msg,
                                      nullptr, nullptr, nullptr);
  for (int d = 0; d < 5; d++) {
    gather_bonds<<<NB / 4, 256, 0, stream>>>(msg, bgraph, nei);
    gemm_k<1><<<2048, 256, 0, stream>>>(nei, wh_t, 512, 64, binput, msg,
                                        nullptr, nullptr, nullptr);
  }
  gather_atoms<<<NA / 4, 256, 0, stream>>>(msg, agraph, fatoms, ainput);
  // out: M=32768 -> 256 mtiles, 32 per XCD
  gemm_k<2><<<1024, 256, 0, stream>>>(ainput, wo_t, 576, 32, nullptr, nullptr,
                                      bo, scope, out);
}